// Round 2
// baseline (77.248 us; speedup 1.0000x reference)
//
#include <hip/hip_runtime.h>
#include <hip/hip_bf16.h>

// ILA layer (fp32 I/O): key = W@ft, query = W@fk (1x1 conv, shared W),
// sim[p,k] = <query[p], key[neighbor_k(p)]> over 9x9 window (zero-padded keys),
// weight = softmax_k(sim)  (OOB entries participate with sim=0),
// out[c,p] = sum_k weight[k] * ft[c, neighbor_k(p)]  (zero-padded ft).
// n=2, c=128, h=w=64, L=9 (81 neighbors).
// R20 = R19 (MFMA weighting) with the tr16 builtin pointer type fixed:
// __builtin_amdgcn_ds_read_tr16_b64_v4f16 wants __fp16 vector_size(8) in AS(3).
// out[p][c] per row-offset r is a banded 16x16x16 matmul
//   A[p][xx] = w[r*9 + (xx-p)] (band), B[xx][c] = ftl tile r.
// ftl re-laid as 8 chunk-tiles of contiguous [16 xx][16 c] halves so the
// B-fragment is one ds_read_b64_tr_b16 per MFMA (per-lane addr = base+8*lane
// delivers B[k=quad*4+j][col=l15], m156/m162-verified layout). 18 tr reads
// prefetched right after B3 (latency hidden under softmax, drained by B4).

#define Hh 64
#define Ww 64
#define Cc 128
#define Nn 2
#define KK 81
#define HW (Hh * Ww)          // 4096
#define CHW (Cc * HW)         // 524288
#define P_TOT (Nn * HW)       // 8192

typedef _Float16 h8 __attribute__((ext_vector_type(8)));
typedef _Float16 h4 __attribute__((ext_vector_type(4)));
typedef float f4v __attribute__((ext_vector_type(4)));

#ifndef __has_builtin
#define __has_builtin(x) 0
#endif

// LDS transpose-read: lane l receives tile[quad*4+j][l&15] of a contiguous
// row-major [16][16] half tile when per-lane addr = tile_base + 8*lane bytes.
#if __has_builtin(__builtin_amdgcn_ds_read_tr16_b64_v4f16)
#define TR_BUILTIN 1
typedef __fp16 g4 __attribute__((__vector_size__(4 * sizeof(__fp16))));
static __device__ __forceinline__ h4 tr16(const _Float16* p) {
    g4 r = __builtin_amdgcn_ds_read_tr16_b64_v4f16(
        (__attribute__((address_space(3))) g4*)p);
    return __builtin_bit_cast(h4, r);
}
#else
#define TR_BUILTIN 0
static __device__ __forceinline__ h4 tr16(const _Float16* p) {
    h4 r;
    asm volatile("ds_read_b64_tr_b16 %0, %1"
                 : "=v"(r)
                 : "v"((__attribute__((address_space(3))) _Float16*)p));
    return r;
}
#endif

// ---------------- Kernel A: projection via MFMA (measured-best version, unchanged).
__global__ __launch_bounds__(256) void proj_kernel(const float* __restrict__ ft,
                                                   const float* __restrict__ fk,
                                                   const float* __restrict__ Wm,
                                                   _Float16* __restrict__ Qbuf,
                                                   _Float16* __restrict__ Kbuf,
                                                   _Float16* __restrict__ fth) {
    __shared__ __align__(16) _Float16 Wth[128 * 136];  // [o][i] fp16 (== B[k][n] view)
    __shared__ __align__(16) _Float16 xkh[32 * 136];   // [px][c] fp16
    __shared__ __align__(16) _Float16 xqh[32 * 136];
    const int t = threadIdx.x;
    const int p0 = blockIdx.x * 32;       // 4096 % 32 == 0: never crosses n
    const int nn = p0 >> 12;
    const int gbase = nn * CHW + (p0 & 4095);

#pragma unroll 4
    for (int e = t; e < 4096; e += 256) {             // stage W -> fp16
        const int n = e >> 5, ch = e & 31;
        const float4 v = *(const float4*)&Wm[n * 128 + (ch << 2)];
        h4 hv; hv[0] = (_Float16)v.x; hv[1] = (_Float16)v.y;
               hv[2] = (_Float16)v.z; hv[3] = (_Float16)v.w;
        *(h4*)&Wth[n * 136 + (ch << 2)] = hv;
    }
#pragma unroll 4
    for (int e = t; e < 1024; e += 256) {             // stage x -> fp16 px-major
        const int c = e >> 3, pc = e & 7;
        const float4 vk = *(const float4*)&ft[gbase + c * HW + (pc << 2)];
        const float4 vq = *(const float4*)&fk[gbase + c * HW + (pc << 2)];
        const int px = pc << 2;
        xkh[(px    ) * 136 + c] = (_Float16)vk.x;
        xkh[(px + 1) * 136 + c] = (_Float16)vk.y;
        xkh[(px + 2) * 136 + c] = (_Float16)vk.z;
        xkh[(px + 3) * 136 + c] = (_Float16)vk.w;
        xqh[(px    ) * 136 + c] = (_Float16)vq.x;
        xqh[(px + 1) * 136 + c] = (_Float16)vq.y;
        xqh[(px + 2) * 136 + c] = (_Float16)vq.z;
        xqh[(px + 3) * 136 + c] = (_Float16)vq.w;
    }
    __syncthreads();

#pragma unroll
    for (int e = t; e < 512; e += 256) {              // fth: coalesced h8 copies
        const int px = e >> 4, cq = e & 15;
        *(h8*)&fth[(size_t)(p0 + px) * 128 + (cq << 3)] =
            *(const h8*)&xkh[px * 136 + (cq << 3)];
    }

    const int lane = t & 63, wv = t >> 6;
    const int quad = lane >> 4, l15 = lane & 15;
    const _Float16* xs = (wv >> 1) ? xqh : xkh;
    _Float16* dst = (wv >> 1) ? Qbuf : Kbuf;
    const int mt = wv & 1;
    const int abase = (mt * 16 + l15) * 136 + (quad << 3);
    const h8 a0 = *(const h8*)&xs[abase];
    const h8 a1 = *(const h8*)&xs[abase + 32];
    const h8 a2 = *(const h8*)&xs[abase + 64];
    const h8 a3 = *(const h8*)&xs[abase + 96];
#pragma unroll
    for (int nt = 0; nt < 8; ++nt) {
        const int bbase = (nt * 16 + l15) * 136 + (quad << 3);
        const h8 b0 = *(const h8*)&Wth[bbase];
        const h8 b1 = *(const h8*)&Wth[bbase + 32];
        const h8 b2 = *(const h8*)&Wth[bbase + 64];
        const h8 b3 = *(const h8*)&Wth[bbase + 96];
        f4v acc = {0.f, 0.f, 0.f, 0.f};
        acc = __builtin_amdgcn_mfma_f32_16x16x32_f16(a0, b0, acc, 0, 0, 0);
        acc = __builtin_amdgcn_mfma_f32_16x16x32_f16(a1, b1, acc, 0, 0, 0);
        acc = __builtin_amdgcn_mfma_f32_16x16x32_f16(a2, b2, acc, 0, 0, 0);
        acc = __builtin_amdgcn_mfma_f32_16x16x32_f16(a3, b3, acc, 0, 0, 0);
        const int col = nt * 16 + l15;
        const size_t rb = (size_t)(p0 + mt * 16 + (quad << 2)) * 128 + col;
#pragma unroll
        for (int r = 0; r < 4; ++r)
            dst[rb + (size_t)r * 128] = (_Float16)acc[r];
    }
}

// ---------------- Kernel B (fused): MFMA dots + softmax + MFMA weighting. 8-px strip.
// ftl tile layout: 8 chunks (16 c each) x 9 r, each a contiguous [16 xx][16 c]
// half tile (256 halves); chunk stride 2312 halves (2304 + 8 pad -> bank spread).
#define FTL_CH 2312
__global__ __launch_bounds__(256, 4) void sim_weight_kernel(const _Float16* __restrict__ Qbuf,
                                                            const _Float16* __restrict__ Kbuf,
                                                            const _Float16* __restrict__ fth,
                                                            float* __restrict__ out) {
    __shared__ __align__(16) unsigned char smem[40720];
    _Float16* Ksw  = (_Float16*)smem;             // 18432 halves [0, 36864)
    _Float16* Qsw  = (_Float16*)(smem + 36864);   // 1024 halves  [36864, 38912); dead after dots
    _Float16* ftl  = (_Float16*)smem;             // 8*2312 = 18496 halves [0, 36992); post-B2c
    float*    simbF= (float*)smem;                // [k][8] fp32, 2592 B — alive B2a..B2c only
    _Float16* simb = (_Float16*)(smem + 39168);   // 648 halves   [39168, 40464)
    float*    redM = (float*)(smem + 40464);      // 32 floats
    float*    redS = (float*)(smem + 40592);      // 32 floats

    const int t  = threadIdx.x;
    const int b  = blockIdx.x;
    const int x0 = (b & 7) << 3;
    const int y  = (b >> 3) & 63;
    const int nn = b >> 9;
    const int pg0 = (nn << 12) + (y << 6) + x0;

    // ---- stage K: zero-padded 9x16 window, h8 copies, XOR-swizzled slots
#pragma unroll 3
    for (int e = t; e < 144 * 16; e += 256) {
        const int v = e >> 4, ci = e & 15;
        const int gx = x0 + (v & 15) - 4;
        const int gy = y + (v >> 4) - 4;
        h8 val = {0, 0, 0, 0, 0, 0, 0, 0};
        if ((unsigned)gx < 64u && (unsigned)gy < 64u)
            val = *(const h8*)&Kbuf[(size_t)((nn << 12) + (gy << 6) + gx) * 128 + (ci << 3)];
        *(h8*)&Ksw[(v << 7) + ((ci ^ (v & 15)) << 3)] = val;
    }
    if (t < 128) {   // stage Q: 8 vectors x 16 chunks
        const int v = t >> 4, ci = t & 15;
        *(h8*)&Qsw[(v << 7) + ((ci ^ v) << 3)] =
            *(const h8*)&Qbuf[(size_t)(pg0 + v) * 128 + (ci << 3)];
    }
    __syncthreads();   // B1

    // ---- PREFETCH ftl source data into registers: overlaps the whole dot phase
    h8 pf[9];
#pragma unroll
    for (int i = 0; i < 9; ++i) {
        const int e = t + (i << 8);               // 9*256 == 144*16 exactly
        const int v = e >> 4, ci = e & 15;
        const int gx = x0 + (v & 15) - 4;
        const int gy = y + (v >> 4) - 4;
        h8 val = {0, 0, 0, 0, 0, 0, 0, 0};
        if ((unsigned)gx < 64u && (unsigned)gy < 64u)
            val = *(const h8*)&fth[(size_t)((nn << 12) + (gy << 6) + gx) * 128 + (ci << 3)];
        pf[i] = val;
    }

    // ---- dots via MFMA: per r, S_r[xx][p] = sum_c Ksw[r*16+xx][c] * Q[p][c]
    // D: row=xx=quad*4+reg, col=p=lane&15 [R13 HW-verified layout].
    const int lane = t & 63, wv = t >> 6;
    const int quad = lane >> 4, l15 = lane & 15;
    const int qrow = l15 & 7;                 // clamp: rows 8-15 duplicate, never extracted
    h8 qb[4];
#pragma unroll
    for (int kc = 0; kc < 4; ++kc) {
        const int ci = (kc << 2) + quad;
        qb[kc] = *(const h8*)&Qsw[(qrow << 7) + ((ci ^ qrow) << 3)];
    }
    const int r0 = wv, r1 = wv + 4;           // r2 = 8 computed by all, extracted by wave 0
    f4v acc0 = {0.f,0.f,0.f,0.f}, acc1 = acc0, acc2 = acc0;
#pragma unroll
    for (int kc = 0; kc < 4; ++kc) {
        const int ci = (kc << 2) + quad;
        const h8 kA = *(const h8*)&Ksw[(((r0 << 4) + l15) << 7) + ((ci ^ l15) << 3)];
        const h8 kB = *(const h8*)&Ksw[(((r1 << 4) + l15) << 7) + ((ci ^ l15) << 3)];
        const h8 kC = *(const h8*)&Ksw[(((8  << 4) + l15) << 7) + ((ci ^ l15) << 3)];
        acc0 = __builtin_amdgcn_mfma_f32_16x16x32_f16(kA, qb[kc], acc0, 0, 0, 0);
        acc1 = __builtin_amdgcn_mfma_f32_16x16x32_f16(kB, qb[kc], acc1, 0, 0, 0);
        acc2 = __builtin_amdgcn_mfma_f32_16x16x32_f16(kC, qb[kc], acc2, 0, 0, 0);
    }
    __syncthreads();   // B2a: MFMA reads done; Ksw/Qsw dead -> simbF may be written

    // extraction: valid iff p=l15<8 and dx=xx-p in [0,9); k = r*9+dx
#pragma unroll
    for (int reg = 0; reg < 4; ++reg) {
        const int xx = (quad << 2) + reg;
        const int dx = xx - l15;
        const bool ok = (l15 < 8) && (dx >= 0) && (dx < 9);
        if (ok)            simbF[(r0 * 9 + dx) * 8 + l15] = acc0[reg];
        if (ok)            simbF[(r1 * 9 + dx) * 8 + l15] = acc1[reg];
        if (ok && wv == 0) simbF[(8  * 9 + dx) * 8 + l15] = acc2[reg];
    }
    __syncthreads();   // B2b: simbF complete

    const int p = t & 7, kb = t >> 3;
    const bool has2 = (kb + 64 < KK);
    const float s0 = simbF[kb * 8 + p];
    const float s1 = simbF[(kb + 32) * 8 + p];
    const float s2 = has2 ? simbF[(kb + 64) * 8 + p] : 0.f;
    __syncthreads();   // B2c: readback done; ftl may overwrite [0, 36992)

    // ---- restage ft from PREFETCHED registers into [chunk][r][xx][16c] tiles
#pragma unroll
    for (int i = 0; i < 9; ++i) {
        const int e = t + (i << 8);
        const int v = e >> 4, ci = e & 15;
        *(h8*)&ftl[(ci >> 1) * FTL_CH + (v << 4) + ((ci & 1) << 3)] = pf[i];
    }

    // ---- softmax in registers: reduce over lanes sharing p (bits 3..5 of lane id)
    float m = fmaxf(s0, s1);
    if (has2) m = fmaxf(m, s2);
#pragma unroll
    for (int off = 8; off <= 32; off <<= 1) m = fmaxf(m, __shfl_xor(m, off));
    if ((t & 56) == 0) redM[((t >> 6) << 3) + p] = m;   // one lane per (wave, p)
    __syncthreads();   // B3 (also covers ftl writes)

    // ---- PREFETCH B-fragments for the weighting MFMAs: 18 tr reads issued now,
    // latency hides under the softmax finish; B4's barrier drain completes them.
    const _Float16* ftc0 = ftl + wv * FTL_CH;          // chunk wv
    const _Float16* ftc1 = ftl + (wv + 4) * FTL_CH;    // chunk wv+4
    h4 bfr[18];
#pragma unroll
    for (int r = 0; r < 9; ++r) {
        bfr[r]     = tr16(ftc0 + (r << 8) + (lane << 2));
        bfr[9 + r] = tr16(ftc1 + (r << 8) + (lane << 2));
    }

    float mm = fmaxf(fmaxf(redM[p], redM[8 + p]), fmaxf(redM[16 + p], redM[24 + p]));
    const float e0 = __expf(s0 - mm);
    const float e1 = __expf(s1 - mm);
    const float e2 = has2 ? __expf(s2 - mm) : 0.f;
    simb[kb * 8 + p] = (_Float16)e0;
    simb[(kb + 32) * 8 + p] = (_Float16)e1;
    if (has2) simb[(kb + 64) * 8 + p] = (_Float16)e2;
    float s = e0 + e1 + e2;
#pragma unroll
    for (int off = 8; off <= 32; off <<= 1) s += __shfl_xor(s, off);
    if ((t & 56) == 0) redS[((t >> 6) << 3) + p] = s;
    __syncthreads();   // B4: simb + redS complete; bfr tr reads drained

#if !TR_BUILTIN
    asm volatile("s_waitcnt lgkmcnt(0)");   // rule-#18 fence for asm-path bfr
    __builtin_amdgcn_sched_barrier(0);
#endif

    // ---- weighting via MFMA: per r, D[p][c] += A[p][xx] * B[xx][c]
    // A[p][xx] = simb[r*9 + (xx-p)][p] on the band 0<=xx-p<9 (rows 8-15 dup'd).
    // Lane (quad,l15): A-frag = A[l15][quad*4+j]; B-frag = tr read (bfr).
    f4v aw0 = {0.f, 0.f, 0.f, 0.f}, aw1 = aw0;
#pragma unroll
    for (int r = 0; r < 9; ++r) {
        h4 afr;
#pragma unroll
        for (int j = 0; j < 4; ++j) {
            const int dx = (quad << 2) + j - qrow;
            const bool ok = (unsigned)dx < 9u;
            afr[j] = ok ? simb[(((r * 9 + dx) << 3) + qrow)] : (_Float16)0.f;
        }
        aw0 = __builtin_amdgcn_mfma_f32_16x16x16f16(afr, bfr[r],     aw0, 0, 0, 0);
        aw1 = __builtin_amdgcn_mfma_f32_16x16x16f16(afr, bfr[9 + r], aw1, 0, 0, 0);
    }

    // D layout: row = p = quad*4+reg (quads 0-1 hold p=0..7), col = c = l15.
    // Rows -> consecutive x => one float4 store per (lane, chunk).
    if (quad < 2) {
        const int q4 = quad << 2;
        const float4 rs0 = *(const float4*)&redS[q4];
        const float4 rs1 = *(const float4*)&redS[8 + q4];
        const float4 rs2 = *(const float4*)&redS[16 + q4];
        const float4 rs3 = *(const float4*)&redS[24 + q4];
        const float iv0 = 1.f / (rs0.x + rs1.x + rs2.x + rs3.x);
        const float iv1 = 1.f / (rs0.y + rs1.y + rs2.y + rs3.y);
        const float iv2 = 1.f / (rs0.z + rs1.z + rs2.z + rs3.z);
        const float iv3 = 1.f / (rs0.w + rs1.w + rs2.w + rs3.w);
        const int xb = (y << 6) + x0 + q4;
        const size_t ob0 = ((size_t)((nn << 7) + (wv << 4) + l15) << 12) + xb;
        const size_t ob1 = ((size_t)((nn << 7) + ((wv + 4) << 4) + l15) << 12) + xb;
        float4 o0, o1;
        o0.x = aw0[0] * iv0; o0.y = aw0[1] * iv1; o0.z = aw0[2] * iv2; o0.w = aw0[3] * iv3;
        o1.x = aw1[0] * iv0; o1.y = aw1[1] * iv1; o1.z = aw1[2] * iv2; o1.w = aw1[3] * iv3;
        *(float4*)&out[ob0] = o0;
        *(float4*)&out[ob1] = o1;
    }
}

extern "C" void kernel_launch(void* const* d_in, const int* in_sizes, int n_in,
                              void* d_out, int out_size, void* d_ws, size_t ws_size,
                              hipStream_t stream) {
    const float* ft = (const float*)d_in[0];
    const float* fk = (const float*)d_in[1];
    const float* Wm = (const float*)d_in[2];
    float* out = (float*)d_out;

    _Float16* wsh  = (_Float16*)d_ws;    // 6 MB: Qh(2MB) + Kh(2MB) + fth(2MB)
    _Float16* Qbuf = wsh;                // [p][c]  8192*128 halves
    _Float16* Kbuf = wsh + 1048576;      // [p][c]  8192*128 halves
    _Float16* fth  = wsh + 2097152;      // fp16 ft, PIXEL-MAJOR [p][c]

    proj_kernel<<<256, 256, 0, stream>>>(ft, fk, Wm, Qbuf, Kbuf, fth);
    sim_weight_kernel<<<1024, 256, 0, stream>>>(Qbuf, Kbuf, fth, out);
}

// Round 3
// 76.791 us; speedup vs baseline: 1.0060x; 1.0060x over previous
//
#include <hip/hip_runtime.h>
#include <hip/hip_bf16.h>

// ILA layer (fp32 I/O): key = W@ft, query = W@fk (1x1 conv, shared W),
// sim[p,k] = <query[p], key[neighbor_k(p)]> over 9x9 window (zero-padded keys),
// weight = softmax_k(sim)  (OOB entries participate with sim=0),
// out[c,p] = sum_k weight[k] * ft[c, neighbor_k(p)]  (zero-padded ft).
// n=2, c=128, h=w=64, L=9 (81 neighbors).
// R21 = R20 (77.2 us) + two latency attacks:
//  (a) proj: 512 blocks x 16 px (was 256 x 32) -> 2 blocks/CU, 2x latency hiding.
//  (b) sim_weight: softmax IN MFMA LAYOUT. Lane (quad,l15) holds
//      S[xx=quad*4+reg][p=l15]; max/sum over xx via shfl_xor(16/32) + per-wave
//      redM/redS partials. Deletes the simbF fp32 round-trip and the (p,kb)
//      readback; barriers 6 -> 3 (B1 stage, B2 dots-done, B3 ftl+simb+redS).

#define Hh 64
#define Ww 64
#define Cc 128
#define Nn 2
#define KK 81
#define HW (Hh * Ww)          // 4096
#define CHW (Cc * HW)         // 524288
#define P_TOT (Nn * HW)       // 8192

typedef _Float16 h8 __attribute__((ext_vector_type(8)));
typedef _Float16 h4 __attribute__((ext_vector_type(4)));
typedef float f4v __attribute__((ext_vector_type(4)));

#ifndef __has_builtin
#define __has_builtin(x) 0
#endif

// LDS transpose-read: lane l receives tile[quad*4+j][l&15] of a contiguous
// row-major [16][16] half tile when per-lane addr = tile_base + 8*lane bytes.
#if __has_builtin(__builtin_amdgcn_ds_read_tr16_b64_v4f16)
#define TR_BUILTIN 1
typedef __fp16 g4 __attribute__((__vector_size__(4 * sizeof(__fp16))));
static __device__ __forceinline__ h4 tr16(const _Float16* p) {
    g4 r = __builtin_amdgcn_ds_read_tr16_b64_v4f16(
        (__attribute__((address_space(3))) g4*)p);
    return __builtin_bit_cast(h4, r);
}
#else
#define TR_BUILTIN 0
static __device__ __forceinline__ h4 tr16(const _Float16* p) {
    h4 r;
    asm volatile("ds_read_b64_tr_b16 %0, %1"
                 : "=v"(r)
                 : "v"((__attribute__((address_space(3))) _Float16*)p));
    return r;
}
#endif

// ---------------- Kernel A: projection via MFMA. 512 blocks x 16 px (2 blocks/CU).
__global__ __launch_bounds__(256) void proj_kernel(const float* __restrict__ ft,
                                                   const float* __restrict__ fk,
                                                   const float* __restrict__ Wm,
                                                   _Float16* __restrict__ Qbuf,
                                                   _Float16* __restrict__ Kbuf,
                                                   _Float16* __restrict__ fth) {
    __shared__ __align__(16) _Float16 Wth[128 * 136];  // [o][i] fp16 (== B[k][n] view)
    __shared__ __align__(16) _Float16 xkh[16 * 136];   // [px][c] fp16
    __shared__ __align__(16) _Float16 xqh[16 * 136];
    const int t = threadIdx.x;
    const int p0 = blockIdx.x * 16;       // 4096 % 16 == 0: never crosses n
    const int nn = p0 >> 12;
    const int gbase = nn * CHW + (p0 & 4095);

#pragma unroll 4
    for (int e = t; e < 4096; e += 256) {             // stage W -> fp16
        const int n = e >> 5, ch = e & 31;
        const float4 v = *(const float4*)&Wm[n * 128 + (ch << 2)];
        h4 hv; hv[0] = (_Float16)v.x; hv[1] = (_Float16)v.y;
               hv[2] = (_Float16)v.z; hv[3] = (_Float16)v.w;
        *(h4*)&Wth[n * 136 + (ch << 2)] = hv;
    }
#pragma unroll
    for (int e = t; e < 512; e += 256) {              // stage x -> fp16 px-major (16 px)
        const int c = e >> 2, pc = e & 3;
        const float4 vk = *(const float4*)&ft[gbase + c * HW + (pc << 2)];
        const float4 vq = *(const float4*)&fk[gbase + c * HW + (pc << 2)];
        const int px = pc << 2;
        xkh[(px    ) * 136 + c] = (_Float16)vk.x;
        xkh[(px + 1) * 136 + c] = (_Float16)vk.y;
        xkh[(px + 2) * 136 + c] = (_Float16)vk.z;
        xkh[(px + 3) * 136 + c] = (_Float16)vk.w;
        xqh[(px    ) * 136 + c] = (_Float16)vq.x;
        xqh[(px + 1) * 136 + c] = (_Float16)vq.y;
        xqh[(px + 2) * 136 + c] = (_Float16)vq.z;
        xqh[(px + 3) * 136 + c] = (_Float16)vq.w;
    }
    __syncthreads();

    {                                                 // fth: coalesced h8 copies (256 e)
        const int px = t >> 4, cq = t & 15;
        *(h8*)&fth[(size_t)(p0 + px) * 128 + (cq << 3)] =
            *(const h8*)&xkh[px * 136 + (cq << 3)];
    }

    const int lane = t & 63, wv = t >> 6;
    const int quad = lane >> 4, l15 = lane & 15;
    const _Float16* xs = (wv >> 1) ? xqh : xkh;
    _Float16* dst = (wv >> 1) ? Qbuf : Kbuf;
    const int nt0 = (wv & 1) << 2;                    // waves split the 8 nt tiles
    const int abase = l15 * 136 + (quad << 3);
    const h8 a0 = *(const h8*)&xs[abase];
    const h8 a1 = *(const h8*)&xs[abase + 32];
    const h8 a2 = *(const h8*)&xs[abase + 64];
    const h8 a3 = *(const h8*)&xs[abase + 96];
#pragma unroll
    for (int ni = 0; ni < 4; ++ni) {
        const int nt = nt0 + ni;
        const int bbase = (nt * 16 + l15) * 136 + (quad << 3);
        const h8 b0 = *(const h8*)&Wth[bbase];
        const h8 b1 = *(const h8*)&Wth[bbase + 32];
        const h8 b2 = *(const h8*)&Wth[bbase + 64];
        const h8 b3 = *(const h8*)&Wth[bbase + 96];
        f4v acc = {0.f, 0.f, 0.f, 0.f};
        acc = __builtin_amdgcn_mfma_f32_16x16x32_f16(a0, b0, acc, 0, 0, 0);
        acc = __builtin_amdgcn_mfma_f32_16x16x32_f16(a1, b1, acc, 0, 0, 0);
        acc = __builtin_amdgcn_mfma_f32_16x16x32_f16(a2, b2, acc, 0, 0, 0);
        acc = __builtin_amdgcn_mfma_f32_16x16x32_f16(a3, b3, acc, 0, 0, 0);
        const int col = nt * 16 + l15;
        const size_t rb = (size_t)(p0 + (quad << 2)) * 128 + col;
#pragma unroll
        for (int r = 0; r < 4; ++r)
            dst[rb + (size_t)r * 128] = (_Float16)acc[r];
    }
}

// ---------------- Kernel B (fused): MFMA dots + in-layout softmax + MFMA weighting.
// ftl tile layout: 8 chunks (16 c each) x 9 r, each a contiguous [16 xx][16 c]
// half tile (256 halves); chunk stride 2312 halves (2304 + 8 pad -> bank spread).
#define FTL_CH 2312
__global__ __launch_bounds__(256, 4) void sim_weight_kernel(const _Float16* __restrict__ Qbuf,
                                                            const _Float16* __restrict__ Kbuf,
                                                            const _Float16* __restrict__ fth,
                                                            float* __restrict__ out) {
    __shared__ __align__(16) unsigned char smem[40720];
    _Float16* Ksw  = (_Float16*)smem;             // 18432 halves [0, 36864)
    _Float16* Qsw  = (_Float16*)(smem + 36864);   // 1024 halves  [36864, 38912); dead after dots
    _Float16* ftl  = (_Float16*)smem;             // 8*2312 = 18496 halves [0, 36992); post-B2
    _Float16* simb = (_Float16*)(smem + 39168);   // 648 halves   [39168, 40464)
    float*    redM = (float*)(smem + 40464);      // 32 floats [wv][p]
    float*    redS = (float*)(smem + 40592);      // 32 floats [wv][p]

    const int t  = threadIdx.x;
    const int b  = blockIdx.x;
    const int x0 = (b & 7) << 3;
    const int y  = (b >> 3) & 63;
    const int nn = b >> 9;
    const int pg0 = (nn << 12) + (y << 6) + x0;

    // ---- stage K: zero-padded 9x16 window, h8 copies, XOR-swizzled slots
#pragma unroll 3
    for (int e = t; e < 144 * 16; e += 256) {
        const int v = e >> 4, ci = e & 15;
        const int gx = x0 + (v & 15) - 4;
        const int gy = y + (v >> 4) - 4;
        h8 val = {0, 0, 0, 0, 0, 0, 0, 0};
        if ((unsigned)gx < 64u && (unsigned)gy < 64u)
            val = *(const h8*)&Kbuf[(size_t)((nn << 12) + (gy << 6) + gx) * 128 + (ci << 3)];
        *(h8*)&Ksw[(v << 7) + ((ci ^ (v & 15)) << 3)] = val;
    }
    if (t < 128) {   // stage Q: 8 vectors x 16 chunks
        const int v = t >> 4, ci = t & 15;
        *(h8*)&Qsw[(v << 7) + ((ci ^ v) << 3)] =
            *(const h8*)&Qbuf[(size_t)(pg0 + v) * 128 + (ci << 3)];
    }
    __syncthreads();   // B1

    // ---- PREFETCH ftl source data into registers: overlaps the whole dot phase
    h8 pf[9];
#pragma unroll
    for (int i = 0; i < 9; ++i) {
        const int e = t + (i << 8);               // 9*256 == 144*16 exactly
        const int v = e >> 4, ci = e & 15;
        const int gx = x0 + (v & 15) - 4;
        const int gy = y + (v >> 4) - 4;
        h8 val = {0, 0, 0, 0, 0, 0, 0, 0};
        if ((unsigned)gx < 64u && (unsigned)gy < 64u)
            val = *(const h8*)&fth[(size_t)((nn << 12) + (gy << 6) + gx) * 128 + (ci << 3)];
        pf[i] = val;
    }

    // ---- dots via MFMA: per r, S_r[xx][p] = sum_c Ksw[r*16+xx][c] * Q[p][c]
    // D: row=xx=quad*4+reg, col=p=lane&15 [R13 HW-verified layout].
    const int lane = t & 63, wv = t >> 6;
    const int quad = lane >> 4, l15 = lane & 15;
    const int qrow = l15 & 7;                 // clamp: rows 8-15 duplicate, never extracted
    h8 qb[4];
#pragma unroll
    for (int kc = 0; kc < 4; ++kc) {
        const int ci = (kc << 2) + quad;
        qb[kc] = *(const h8*)&Qsw[(qrow << 7) + ((ci ^ qrow) << 3)];
    }
    const int r0 = wv, r1 = wv + 4;           // r2 = 8 computed by all, owned by wave 0
    f4v acc0 = {0.f,0.f,0.f,0.f}, acc1 = acc0, acc2 = acc0;
#pragma unroll
    for (int kc = 0; kc < 4; ++kc) {
        const int ci = (kc << 2) + quad;
        const h8 kA = *(const h8*)&Ksw[(((r0 << 4) + l15) << 7) + ((ci ^ l15) << 3)];
        const h8 kB = *(const h8*)&Ksw[(((r1 << 4) + l15) << 7) + ((ci ^ l15) << 3)];
        const h8 kC = *(const h8*)&Ksw[(((8  << 4) + l15) << 7) + ((ci ^ l15) << 3)];
        acc0 = __builtin_amdgcn_mfma_f32_16x16x32_f16(kA, qb[kc], acc0, 0, 0, 0);
        acc1 = __builtin_amdgcn_mfma_f32_16x16x32_f16(kB, qb[kc], acc1, 0, 0, 0);
        acc2 = __builtin_amdgcn_mfma_f32_16x16x32_f16(kC, qb[kc], acc2, 0, 0, 0);
    }

    // ---- in-layout softmax, phase 1: per-lane band-masked max over xx, then quads
    float m = -3.0e38f;
#pragma unroll
    for (int reg = 0; reg < 4; ++reg) {
        const int dx = (quad << 2) + reg - l15;         // xx - p
        const bool ok = (l15 < 8) && ((unsigned)dx < 9u);
        if (ok) {
            m = fmaxf(m, fmaxf(acc0[reg], acc1[reg]));  // r=wv, wv+4
            m = fmaxf(m, acc2[reg]);                    // r=8 (same in all waves; max-safe)
        }
    }
    m = fmaxf(m, __shfl_xor(m, 16));
    m = fmaxf(m, __shfl_xor(m, 32));
    if (quad == 0 && l15 < 8) redM[(wv << 3) + l15] = m;
    __syncthreads();   // B2: dots' LDS reads done (Ksw/Qsw dead); redM complete

    // ---- restage ft from PREFETCHED registers into [chunk][r][xx][16c] tiles
#pragma unroll
    for (int i = 0; i < 9; ++i) {
        const int e = t + (i << 8);
        const int v = e >> 4, ci = e & 15;
        *(h8*)&ftl[(ci >> 1) * FTL_CH + (v << 4) + ((ci & 1) << 3)] = pf[i];
    }

    // ---- phase 2: exp + write simb (fp16) + band-masked sum over xx, then quads
    const float mm = fmaxf(fmaxf(redM[qrow], redM[8 + qrow]),
                           fmaxf(redM[16 + qrow], redM[24 + qrow]));
    float ssum = 0.f;
#pragma unroll
    for (int reg = 0; reg < 4; ++reg) {
        const int dx = (quad << 2) + reg - l15;
        const bool ok = (l15 < 8) && ((unsigned)dx < 9u);
        const float e0 = ok ? __expf(acc0[reg] - mm) : 0.f;
        const float e1 = ok ? __expf(acc1[reg] - mm) : 0.f;
        const float e2 = (ok && wv == 0) ? __expf(acc2[reg] - mm) : 0.f;
        if (ok)            simb[((r0 * 9 + dx) << 3) + l15] = (_Float16)e0;
        if (ok)            simb[((r1 * 9 + dx) << 3) + l15] = (_Float16)e1;
        if (ok && wv == 0) simb[((8  * 9 + dx) << 3) + l15] = (_Float16)e2;
        ssum += e0 + e1 + e2;
    }
    ssum += __shfl_xor(ssum, 16);
    ssum += __shfl_xor(ssum, 32);
    if (quad == 0 && l15 < 8) redS[(wv << 3) + l15] = ssum;
    __syncthreads();   // B3: ftl + simb + redS complete

    // ---- B-fragments for the weighting MFMAs: 18 tr reads
    const _Float16* ftc0 = ftl + wv * FTL_CH;          // chunk wv
    const _Float16* ftc1 = ftl + (wv + 4) * FTL_CH;    // chunk wv+4
    h4 bfr[18];
#pragma unroll
    for (int r = 0; r < 9; ++r) {
        bfr[r]     = tr16(ftc0 + (r << 8) + (lane << 2));
        bfr[9 + r] = tr16(ftc1 + (r << 8) + (lane << 2));
    }

#if !TR_BUILTIN
    asm volatile("s_waitcnt lgkmcnt(0)");   // rule-#18 fence for asm-path bfr
    __builtin_amdgcn_sched_barrier(0);
#endif

    // ---- weighting via MFMA: per r, D[p][c] += A[p][xx] * B[xx][c]
    // A[p][xx] = simb[r*9 + (xx-p)][p] on the band 0<=xx-p<9 (rows 8-15 dup'd).
    // Lane (quad,l15): A-frag = A[l15][quad*4+j]; B-frag = tr read (bfr).
    f4v aw0 = {0.f, 0.f, 0.f, 0.f}, aw1 = aw0;
#pragma unroll
    for (int r = 0; r < 9; ++r) {
        h4 afr;
#pragma unroll
        for (int j = 0; j < 4; ++j) {
            const int dx = (quad << 2) + j - qrow;
            const bool ok = (unsigned)dx < 9u;
            afr[j] = ok ? simb[(((r * 9 + dx) << 3) + qrow)] : (_Float16)0.f;
        }
        aw0 = __builtin_amdgcn_mfma_f32_16x16x16f16(afr, bfr[r],     aw0, 0, 0, 0);
        aw1 = __builtin_amdgcn_mfma_f32_16x16x16f16(afr, bfr[9 + r], aw1, 0, 0, 0);
    }

    // D layout: row = p = quad*4+reg (quads 0-1 hold p=0..7), col = c = l15.
    // Rows -> consecutive x => one float4 store per (lane, chunk).
    if (quad < 2) {
        const int q4 = quad << 2;
        const float4 rs0 = *(const float4*)&redS[q4];
        const float4 rs1 = *(const float4*)&redS[8 + q4];
        const float4 rs2 = *(const float4*)&redS[16 + q4];
        const float4 rs3 = *(const float4*)&redS[24 + q4];
        const float iv0 = 1.f / (rs0.x + rs1.x + rs2.x + rs3.x);
        const float iv1 = 1.f / (rs0.y + rs1.y + rs2.y + rs3.y);
        const float iv2 = 1.f / (rs0.z + rs1.z + rs2.z + rs3.z);
        const float iv3 = 1.f / (rs0.w + rs1.w + rs2.w + rs3.w);
        const int xb = (y << 6) + x0 + q4;
        const size_t ob0 = ((size_t)((nn << 7) + (wv << 4) + l15) << 12) + xb;
        const size_t ob1 = ((size_t)((nn << 7) + ((wv + 4) << 4) + l15) << 12) + xb;
        float4 o0, o1;
        o0.x = aw0[0] * iv0; o0.y = aw0[1] * iv1; o0.z = aw0[2] * iv2; o0.w = aw0[3] * iv3;
        o1.x = aw1[0] * iv0; o1.y = aw1[1] * iv1; o1.z = aw1[2] * iv2; o1.w = aw1[3] * iv3;
        *(float4*)&out[ob0] = o0;
        *(float4*)&out[ob1] = o1;
    }
}

extern "C" void kernel_launch(void* const* d_in, const int* in_sizes, int n_in,
                              void* d_out, int out_size, void* d_ws, size_t ws_size,
                              hipStream_t stream) {
    const float* ft = (const float*)d_in[0];
    const float* fk = (const float*)d_in[1];
    const float* Wm = (const float*)d_in[2];
    float* out = (float*)d_out;

    _Float16* wsh  = (_Float16*)d_ws;    // 6 MB: Qh(2MB) + Kh(2MB) + fth(2MB)
    _Float16* Qbuf = wsh;                // [p][c]  8192*128 halves
    _Float16* Kbuf = wsh + 1048576;      // [p][c]  8192*128 halves
    _Float16* fth  = wsh + 2097152;      // fp16 ft, PIXEL-MAJOR [p][c]

    proj_kernel<<<512, 256, 0, stream>>>(ft, fk, Wm, Qbuf, Kbuf, fth);
    sim_weight_kernel<<<1024, 256, 0, stream>>>(Qbuf, Kbuf, fth, out);
}